// Round 5
// baseline (411.202 us; speedup 1.0000x reference)
//
#include <hip/hip_runtime.h>
#include <stdint.h>

// FLASH_6073083756839 — fp16 MFMA pipeline, 32x32x16 MFMA + BK=64 (R5).
//  prep:    cast X->fp16; transpose+cast W_uv -> Wuvt[f][h]; W_out -> Wt[h][e]
//  mfma<0>: u/v GEMM (N=4096): u(fp16 [M][E]), v_t(fp16 [b][e][s])
//  mfma<4>: q,k GEMM (base 128 cols)
//  mfma<1>: sq = fp16( (relu(q@k^T)*2^6)^2 )  == relu(scores/S)^2 * 2^34
//  mfma<2>: p = fp16( u * (sq @ v_t^T) )      (carries 2^34 scale)
//  mfma<3>: out = (p @ Wt^T) * 2^-34 + b_out  (fp32)

#define H_DIM  1024
#define E_DIM  2048
#define SD     128
#define B_SZ   4
#define S_LEN  2048
#define M_TOT  (B_SZ * S_LEN)          // 8192
#define F_DIM  (2 * E_DIM + SD)        // 4224

typedef _Float16 f16;
typedef __attribute__((ext_vector_type(4))) _Float16 f16x4;
typedef __attribute__((ext_vector_type(8))) _Float16 f16x8;
typedef __attribute__((ext_vector_type(16))) float f32x16;

__device__ __forceinline__ float silu_f(float x) { return x / (1.f + __expf(-x)); }

__device__ __forceinline__ void gload16(const void* g, void* l) {
  __builtin_amdgcn_global_load_lds(
      (const __attribute__((address_space(1))) void*)(uintptr_t)g,
      (__attribute__((address_space(3))) void*)(uint32_t)(uintptr_t)l,
      16, 0, 0);
}

// ---------------- prep kernels ----------------
__global__ __launch_bounds__(256) void cast_f16_k(const float* __restrict__ src,
                                                  f16* __restrict__ dst, long n) {
  long i = ((long)blockIdx.x * 256 + threadIdx.x) * 4;
  if (i < n) {
    float4 v = *(const float4*)(src + i);
    f16x4 h; h[0] = (f16)v.x; h[1] = (f16)v.y; h[2] = (f16)v.z; h[3] = (f16)v.w;
    *(f16x4*)(dst + i) = h;
  }
}

// dst[c][r] = (f16) src[r][c]; src is R x C
__global__ __launch_bounds__(256) void transpose_cast_k(const float* __restrict__ src,
                                                        f16* __restrict__ dst, int R, int C) {
  __shared__ float tile[32][33];
  int c0 = blockIdx.x * 32, r0 = blockIdx.y * 32;
  int tx = threadIdx.x & 31, ty = threadIdx.x >> 5;  // ty 0..7
  for (int i = ty; i < 32; i += 8) tile[i][tx] = src[(long)(r0 + i) * C + c0 + tx];
  __syncthreads();
  for (int i = ty; i < 32; i += 8) dst[(long)(c0 + i) * R + r0 + tx] = (f16)tile[tx][i];
}

// ---------------- fp16 MFMA GEMM, 32x32x16, BK=64 ----------------
// A: [m][k] fp16, row stride = K.  B: [n][k] fp16 (pre-transposed), row stride = K.
//  MODE 0: K=1024, N=4096, u/v epilogue.   MODE 1: K=128,  scores->sq.
//  MODE 2: K=2048, p = u*(sq@v^T).         MODE 3: K=2048, out fp32.
//  MODE 4: K=1024, N=128, q/k epilogue.
template <int MODE>
__global__ __launch_bounds__(256) void mfma_gemm(
    const f16* __restrict__ Ag, const f16* __restrict__ Bg,
    float* __restrict__ F0, f16* __restrict__ H0, const f16* __restrict__ H1,
    f16* __restrict__ H2, f16* __restrict__ H3,
    const float* __restrict__ C0, const float* __restrict__ C1,
    const float* __restrict__ C2)
{
  constexpr int K   = (MODE == 1) ? SD : (MODE == 0 || MODE == 4) ? H_DIM : 2048;
  constexpr int LDA = K, LDB = K;

  __shared__ f16 As[2][128][32];   // [k-half][row][k32]
  __shared__ f16 Bs[2][128][32];

  const int t    = threadIdx.x;
  const int w    = t >> 6;
  const int lane = t & 63;
  const int lo5  = lane & 31;
  const int hi   = lane >> 5;         // 0/1 : k-half within a 16-k MFMA step
  const int wy   = w >> 1, wx = w & 1;
  const int m0   = blockIdx.y * 128;
  const int n0   = blockIdx.x * 128;
  const long z   = blockIdx.z;

  const f16* A = Ag + (MODE == 1 ? z * (long)S_LEN * SD
                     : MODE == 2 ? z * (long)S_LEN * S_LEN : 0);
  const f16* B = Bg + (MODE == 1 ? z * (long)S_LEN * SD
                     : MODE == 2 ? z * (long)E_DIM * S_LEN : 0);

  const int srow = lane >> 2;        // 0..15
  const int scol = (lane & 3) * 8;   // f16 elems (16B chunks)

  f32x16 acc[2][2] = {};

  for (int k0 = 0; k0 < K; k0 += 64) {
#pragma unroll
    for (int h = 0; h < 2; h++)
#pragma unroll
      for (int g16 = 0; g16 < 2; g16++) {
        const int r = (w << 5) + (g16 << 4);
        gload16(A + (long)(m0 + r + srow) * LDA + k0 + (h << 5) + scol, &As[h][r][0]);
        gload16(B + (long)(n0 + r + srow) * LDB + k0 + (h << 5) + scol, &Bs[h][r][0]);
      }
    __syncthreads();

#pragma unroll
    for (int ks = 0; ks < 4; ks++) {
      const int h  = ks >> 1;
      const int kc = (ks & 1) * 16 + (hi << 3);
      f16x8 av[2], bv[2];
#pragma unroll
      for (int i = 0; i < 2; i++)
        av[i] = *(const f16x8*)&As[h][(wy << 6) + (i << 5) + lo5][kc];
#pragma unroll
      for (int j = 0; j < 2; j++)
        bv[j] = *(const f16x8*)&Bs[h][(wx << 6) + (j << 5) + lo5][kc];
#pragma unroll
      for (int i = 0; i < 2; i++)
#pragma unroll
        for (int j = 0; j < 2; j++)
          acc[i][j] = __builtin_amdgcn_mfma_f32_32x32x16_f16(av[i], bv[j], acc[i][j], 0, 0, 0);
    }
    __syncthreads();
  }

  // C/D layout (32x32): col = lane&31, row = (reg&3) + 8*(reg>>2) + 4*(lane>>5)
  const int rb0 = m0 + (wy << 6) + (hi << 2);   // + i*32 + g*8 + rr
  const int cb0 = n0 + (wx << 6) + lo5;         // + j*32

  if (MODE == 0) {
    if (n0 < E_DIM) {                 // u region: fp16 row-major [M][E]
#pragma unroll
      for (int i = 0; i < 2; i++)
#pragma unroll
        for (int j = 0; j < 2; j++) {
          int gc = cb0 + (j << 5);
          float bias = C0[gc];
#pragma unroll
          for (int g = 0; g < 4; g++)
#pragma unroll
            for (int rr = 0; rr < 4; rr++) {
              int gr = rb0 + (i << 5) + (g << 3) + rr;
              H0[(long)gr * E_DIM + gc] = (f16)silu_f(acc[i][j][g * 4 + rr] + bias);
            }
        }
    } else {                          // v region: fp16, transposed [b][e][s]
#pragma unroll
      for (int i = 0; i < 2; i++) {
#pragma unroll
        for (int j = 0; j < 2; j++) {
          int gc = cb0 + (j << 5);
          float bias = C0[gc];
#pragma unroll
          for (int g = 0; g < 4; g++) {
            int gr0 = rb0 + (i << 5) + (g << 3);       // 4 consecutive rows from here
            int b   = gr0 >> 11;
            int s0  = gr0 & (S_LEN - 1);
            f16x4 pk;
#pragma unroll
            for (int rr = 0; rr < 4; rr++) pk[rr] = (f16)silu_f(acc[i][j][g * 4 + rr] + bias);
            *(f16x4*)&H1[((long)b * E_DIM + (gc - E_DIM)) * S_LEN + s0] = pk;
          }
        }
      }
    }
  } else if (MODE == 4) {             // q,k from base cols (N=128)
#pragma unroll
    for (int i = 0; i < 2; i++)
#pragma unroll
      for (int j = 0; j < 2; j++) {
        int jj = cb0 + (j << 5);      // 0..127
        float bias = C0[jj];
        float g0 = C1[jj], g1 = C1[SD + jj];
        float be0 = C2[jj], be1 = C2[SD + jj];
#pragma unroll
        for (int g = 0; g < 4; g++)
#pragma unroll
          for (int rr = 0; rr < 4; rr++) {
            int gr = rb0 + (i << 5) + (g << 3) + rr;
            float s = silu_f(acc[i][j][g * 4 + rr] + bias);
            H2[(long)gr * SD + jj] = (f16)(s * g0 + be0);   // q
            H3[(long)gr * SD + jj] = (f16)(s * g1 + be1);   // k
          }
      }
  } else if (MODE == 1) {             // sq = (relu(q·k)*64)^2  (carries 2^34)
#pragma unroll
    for (int i = 0; i < 2; i++)
#pragma unroll
      for (int j = 0; j < 2; j++) {
        int gc = cb0 + (j << 5);
#pragma unroll
        for (int g = 0; g < 4; g++)
#pragma unroll
          for (int rr = 0; rr < 4; rr++) {
            int gr = rb0 + (i << 5) + (g << 3) + rr;
            float tv = fmaxf(acc[i][j][g * 4 + rr], 0.f) * 64.f;
            H0[z * (long)S_LEN * S_LEN + (long)gr * S_LEN + gc] = (f16)(tv * tv);
          }
      }
  } else if (MODE == 2) {             // p = fp16(u * attn_v_scaled)
    const long rowoff = z * S_LEN;
#pragma unroll
    for (int i = 0; i < 2; i++)
#pragma unroll
      for (int j = 0; j < 2; j++) {
        int gc = cb0 + (j << 5);
#pragma unroll
        for (int g = 0; g < 4; g++)
#pragma unroll
          for (int rr = 0; rr < 4; rr++) {
            int gr = rb0 + (i << 5) + (g << 3) + rr;
            long idx = (rowoff + gr) * (long)E_DIM + gc;
            H0[idx] = (f16)((float)H1[idx] * acc[i][j][g * 4 + rr]);
          }
      }
  } else {                            // MODE 3: out = acc*2^-34 + b_out (fp32)
#pragma unroll
    for (int i = 0; i < 2; i++)
#pragma unroll
      for (int j = 0; j < 2; j++) {
        int gc = cb0 + (j << 5);
        float bias = C0[gc];
#pragma unroll
        for (int g = 0; g < 4; g++)
#pragma unroll
          for (int rr = 0; rr < 4; rr++) {
            int gr = rb0 + (i << 5) + (g << 3) + rr;
            F0[(long)gr * H_DIM + gc] = acc[i][j][g * 4 + rr] * (1.0f / 17179869184.0f) + bias;
          }
      }
  }
}

extern "C" void kernel_launch(void* const* d_in, const int* in_sizes, int n_in,
                              void* d_out, int out_size, void* d_ws, size_t ws_size,
                              hipStream_t stream) {
  const float* X     = (const float*)d_in[0];
  const float* W_uv  = (const float*)d_in[1];
  const float* b_uv  = (const float*)d_in[2];
  const float* gamma = (const float*)d_in[3];
  const float* beta  = (const float*)d_in[4];
  const float* W_out = (const float*)d_in[5];
  const float* b_out = (const float*)d_in[6];
  float* out = (float*)d_out;

  char* wp = (char*)d_ws;
  f16* Xh   = (f16*)wp; wp += (long)M_TOT * H_DIM * 2;        // 16 MB
  f16* Wuvt = (f16*)wp; wp += (long)F_DIM * H_DIM * 2;        // 8.65 MB
  f16* Wt   = (f16*)wp; wp += (long)H_DIM * E_DIM * 2;        // 4 MB
  f16* u    = (f16*)wp; wp += (long)M_TOT * E_DIM * 2;        // 32 MB
  f16* vt   = (f16*)wp; wp += (long)M_TOT * E_DIM * 2;        // 32 MB
  f16* qh   = (f16*)wp; wp += (long)M_TOT * SD * 2;           // 2 MB
  f16* kh   = (f16*)wp; wp += (long)M_TOT * SD * 2;           // 2 MB
  f16* sq   = (f16*)wp; wp += (long)B_SZ * S_LEN * S_LEN * 2; // 32 MB
  f16* p    = (f16*)wp; wp += (long)M_TOT * E_DIM * 2;        // 32 MB

  // prep
  cast_f16_k<<<(M_TOT * H_DIM) / (256 * 4), 256, 0, stream>>>(X, Xh, (long)M_TOT * H_DIM);
  transpose_cast_k<<<dim3(F_DIM / 32, H_DIM / 32), 256, 0, stream>>>(W_uv, Wuvt, H_DIM, F_DIM);
  transpose_cast_k<<<dim3(H_DIM / 32, E_DIM / 32), 256, 0, stream>>>(W_out, Wt, E_DIM, H_DIM);

  // u, v_t  (N=4096, slim epilogue)
  mfma_gemm<0><<<dim3(2 * E_DIM / 128, M_TOT / 128, 1), 256, 0, stream>>>(
      Xh, Wuvt, nullptr, u, vt, nullptr, nullptr, b_uv, nullptr, nullptr);

  // q, k  (base 128 cols of W_uv)
  mfma_gemm<4><<<dim3(1, M_TOT / 128, 1), 256, 0, stream>>>(
      Xh, Wuvt + (long)2 * E_DIM * H_DIM, nullptr, nullptr, nullptr, qh, kh,
      b_uv + 2 * E_DIM, gamma, beta);

  // sq = (relu(q@k^T)*2^6)^2
  mfma_gemm<1><<<dim3(S_LEN / 128, S_LEN / 128, B_SZ), 256, 0, stream>>>(
      qh, kh, nullptr, sq, nullptr, nullptr, nullptr, nullptr, nullptr, nullptr);

  // p = u * (sq @ v)
  mfma_gemm<2><<<dim3(E_DIM / 128, S_LEN / 128, B_SZ), 256, 0, stream>>>(
      sq, vt, nullptr, p, u, nullptr, nullptr, nullptr, nullptr, nullptr);

  // out = p @ W_out * 2^-34 + b_out
  mfma_gemm<3><<<dim3(H_DIM / 128, M_TOT / 128, 1), 256, 0, stream>>>(
      p, Wt, out, nullptr, nullptr, nullptr, nullptr, b_out, nullptr, nullptr);
}

// Round 6
// 368.580 us; speedup vs baseline: 1.1156x; 1.1156x over previous
//
#include <hip/hip_runtime.h>
#include <stdint.h>

// FLASH_6073083756839 — fp16 MFMA, 32x32x16 + BK=64 + XOR LDS swizzle (R6).
//  LDS chunk swizzle: physical 16B slot p at row r holds logical chunk
//  p ^ ((r>>1)&3). Realized on the store side via per-lane global column
//  selection (global_load_lds: LDS dst is lane-ordered, global addr is free).
//  Spreads fragment-column reads across all 8 bank groups (conflict-free b128).
//
//  mfma<0>: u/v GEMM (N=4096): u(fp16 [M][E]), v_t(fp16 [b][e][s])
//  mfma<4>: q,k GEMM (base 128 cols)
//  mfma<1>: sq = fp16( (relu(q@k^T)*2^6)^2 )  == relu(scores/S)^2 * 2^34
//  mfma<2>: p = fp16( u * (sq @ v_t^T) )      (carries 2^34 scale)
//  mfma<3>: out = (p @ Wt^T) * 2^-34 + b_out  (fp32)

#define H_DIM  1024
#define E_DIM  2048
#define SD     128
#define B_SZ   4
#define S_LEN  2048
#define M_TOT  (B_SZ * S_LEN)          // 8192
#define F_DIM  (2 * E_DIM + SD)        // 4224

typedef _Float16 f16;
typedef __attribute__((ext_vector_type(4))) _Float16 f16x4;
typedef __attribute__((ext_vector_type(8))) _Float16 f16x8;
typedef __attribute__((ext_vector_type(16))) float f32x16;

__device__ __forceinline__ float silu_f(float x) { return x / (1.f + __expf(-x)); }

__device__ __forceinline__ void gload16(const void* g, void* l) {
  __builtin_amdgcn_global_load_lds(
      (const __attribute__((address_space(1))) void*)(uintptr_t)g,
      (__attribute__((address_space(3))) void*)(uint32_t)(uintptr_t)l,
      16, 0, 0);
}

// ---------------- prep kernels ----------------
__global__ __launch_bounds__(256) void cast_f16_k(const float* __restrict__ src,
                                                  f16* __restrict__ dst, long n) {
  long i = ((long)blockIdx.x * 256 + threadIdx.x) * 4;
  if (i < n) {
    float4 v = *(const float4*)(src + i);
    f16x4 h; h[0] = (f16)v.x; h[1] = (f16)v.y; h[2] = (f16)v.z; h[3] = (f16)v.w;
    *(f16x4*)(dst + i) = h;
  }
}

// dst[c][r] = (f16) src[r][c]; src is R x C
__global__ __launch_bounds__(256) void transpose_cast_k(const float* __restrict__ src,
                                                        f16* __restrict__ dst, int R, int C) {
  __shared__ float tile[32][33];
  int c0 = blockIdx.x * 32, r0 = blockIdx.y * 32;
  int tx = threadIdx.x & 31, ty = threadIdx.x >> 5;  // ty 0..7
  for (int i = ty; i < 32; i += 8) tile[i][tx] = src[(long)(r0 + i) * C + c0 + tx];
  __syncthreads();
  for (int i = ty; i < 32; i += 8) dst[(long)(c0 + i) * R + r0 + tx] = (f16)tile[tx][i];
}

// ---------------- fp16 MFMA GEMM, 32x32x16, BK=64, swizzled LDS ----------------
// A: [m][k] fp16, row stride = K.  B: [n][k] fp16 (pre-transposed), row stride = K.
//  MODE 0: K=1024, N=4096, u/v epilogue.   MODE 1: K=128,  scores->sq.
//  MODE 2: K=2048, p = u*(sq@v^T).         MODE 3: K=2048, out fp32.
//  MODE 4: K=1024, N=128, q/k epilogue.
template <int MODE>
__global__ __launch_bounds__(256) void mfma_gemm(
    const f16* __restrict__ Ag, const f16* __restrict__ Bg,
    float* __restrict__ F0, f16* __restrict__ H0, const f16* __restrict__ H1,
    f16* __restrict__ H2, f16* __restrict__ H3,
    const float* __restrict__ C0, const float* __restrict__ C1,
    const float* __restrict__ C2)
{
  constexpr int K   = (MODE == 1) ? SD : (MODE == 0 || MODE == 4) ? H_DIM : 2048;
  constexpr int LDA = K, LDB = K;

  __shared__ f16 As[2][128][32];   // [k-half][row][k32]  (chunks XOR-swizzled)
  __shared__ f16 Bs[2][128][32];

  const int t    = threadIdx.x;
  const int w    = t >> 6;
  const int lane = t & 63;
  const int lo5  = lane & 31;
  const int hi   = lane >> 5;         // 0/1 : k-half within a 16-k MFMA step
  const int wy   = w >> 1, wx = w & 1;
  const int m0   = blockIdx.y * 128;
  const int n0   = blockIdx.x * 128;
  const long z   = blockIdx.z;

  const f16* A = Ag + (MODE == 1 ? z * (long)S_LEN * SD
                     : MODE == 2 ? z * (long)S_LEN * S_LEN : 0);
  const f16* B = Bg + (MODE == 1 ? z * (long)S_LEN * SD
                     : MODE == 2 ? z * (long)E_DIM * S_LEN : 0);

  const int srow = lane >> 2;                                  // 0..15
  // swizzled global column: logical chunk = (lane&3) ^ ((srow>>1)&3)
  const int scol = (((lane & 3) ^ ((srow >> 1) & 3))) * 8;     // f16 elems
  // reader-side swizzle term (row = ...+lo5; 32-multiples vanish mod 4)
  const int rsw  = (lo5 >> 1) & 3;

  f32x16 acc[2][2] = {};

  for (int k0 = 0; k0 < K; k0 += 64) {
#pragma unroll
    for (int h = 0; h < 2; h++)
#pragma unroll
      for (int g16 = 0; g16 < 2; g16++) {
        const int r = (w << 5) + (g16 << 4);
        gload16(A + (long)(m0 + r + srow) * LDA + k0 + (h << 5) + scol, &As[h][r][0]);
        gload16(B + (long)(n0 + r + srow) * LDB + k0 + (h << 5) + scol, &Bs[h][r][0]);
      }
    __syncthreads();

#pragma unroll
    for (int ks = 0; ks < 4; ks++) {
      const int h  = ks >> 1;
      const int cl = ((ks & 1) << 1) + hi;          // logical 16B chunk 0..3
      const int kc = (cl ^ rsw) << 3;               // physical f16 column
      f16x8 av[2], bv[2];
#pragma unroll
      for (int i = 0; i < 2; i++)
        av[i] = *(const f16x8*)&As[h][(wy << 6) + (i << 5) + lo5][kc];
#pragma unroll
      for (int j = 0; j < 2; j++)
        bv[j] = *(const f16x8*)&Bs[h][(wx << 6) + (j << 5) + lo5][kc];
#pragma unroll
      for (int i = 0; i < 2; i++)
#pragma unroll
        for (int j = 0; j < 2; j++)
          acc[i][j] = __builtin_amdgcn_mfma_f32_32x32x16_f16(av[i], bv[j], acc[i][j], 0, 0, 0);
    }
    __syncthreads();
  }

  // C/D layout (32x32): col = lane&31, row = (reg&3) + 8*(reg>>2) + 4*(lane>>5)
  const int rb0 = m0 + (wy << 6) + (hi << 2);   // + i*32 + g*8 + rr
  const int cb0 = n0 + (wx << 6) + lo5;         // + j*32

  if (MODE == 0) {
    if (n0 < E_DIM) {                 // u region: fp16 row-major [M][E]
#pragma unroll
      for (int i = 0; i < 2; i++)
#pragma unroll
        for (int j = 0; j < 2; j++) {
          int gc = cb0 + (j << 5);
          float bias = C0[gc];
#pragma unroll
          for (int g = 0; g < 4; g++)
#pragma unroll
            for (int rr = 0; rr < 4; rr++) {
              int gr = rb0 + (i << 5) + (g << 3) + rr;
              H0[(long)gr * E_DIM + gc] = (f16)silu_f(acc[i][j][g * 4 + rr] + bias);
            }
        }
    } else {                          // v region: fp16, transposed [b][e][s]
#pragma unroll
      for (int i = 0; i < 2; i++) {
#pragma unroll
        for (int j = 0; j < 2; j++) {
          int gc = cb0 + (j << 5);
          float bias = C0[gc];
#pragma unroll
          for (int g = 0; g < 4; g++) {
            int gr0 = rb0 + (i << 5) + (g << 3);       // 4 consecutive rows
            int b   = gr0 >> 11;
            int s0  = gr0 & (S_LEN - 1);
            f16x4 pk;
#pragma unroll
            for (int rr = 0; rr < 4; rr++) pk[rr] = (f16)silu_f(acc[i][j][g * 4 + rr] + bias);
            *(f16x4*)&H1[((long)b * E_DIM + (gc - E_DIM)) * S_LEN + s0] = pk;
          }
        }
      }
    }
  } else if (MODE == 4) {             // q,k from base cols (N=128)
#pragma unroll
    for (int i = 0; i < 2; i++)
#pragma unroll
      for (int j = 0; j < 2; j++) {
        int jj = cb0 + (j << 5);      // 0..127
        float bias = C0[jj];
        float g0 = C1[jj], g1 = C1[SD + jj];
        float be0 = C2[jj], be1 = C2[SD + jj];
#pragma unroll
        for (int g = 0; g < 4; g++)
#pragma unroll
          for (int rr = 0; rr < 4; rr++) {
            int gr = rb0 + (i << 5) + (g << 3) + rr;
            float s = silu_f(acc[i][j][g * 4 + rr] + bias);
            H2[(long)gr * SD + jj] = (f16)(s * g0 + be0);   // q
            H3[(long)gr * SD + jj] = (f16)(s * g1 + be1);   // k
          }
      }
  } else if (MODE == 1) {             // sq = (relu(q·k)*64)^2  (carries 2^34)
#pragma unroll
    for (int i = 0; i < 2; i++)
#pragma unroll
      for (int j = 0; j < 2; j++) {
        int gc = cb0 + (j << 5);
#pragma unroll
        for (int g = 0; g < 4; g++)
#pragma unroll
          for (int rr = 0; rr < 4; rr++) {
            int gr = rb0 + (i << 5) + (g << 3) + rr;
            float tv = fmaxf(acc[i][j][g * 4 + rr], 0.f) * 64.f;
            H0[z * (long)S_LEN * S_LEN + (long)gr * S_LEN + gc] = (f16)(tv * tv);
          }
      }
  } else if (MODE == 2) {             // p = fp16(u * attn_v_scaled)
    const long rowoff = z * S_LEN;
#pragma unroll
    for (int i = 0; i < 2; i++)
#pragma unroll
      for (int j = 0; j < 2; j++) {
        int gc = cb0 + (j << 5);
#pragma unroll
        for (int g = 0; g < 4; g++)
#pragma unroll
          for (int rr = 0; rr < 4; rr++) {
            int gr = rb0 + (i << 5) + (g << 3) + rr;
            long idx = (rowoff + gr) * (long)E_DIM + gc;
            H0[idx] = (f16)((float)H1[idx] * acc[i][j][g * 4 + rr]);
          }
      }
  } else {                            // MODE 3: out = acc*2^-34 + b_out (fp32)
#pragma unroll
    for (int i = 0; i < 2; i++)
#pragma unroll
      for (int j = 0; j < 2; j++) {
        int gc = cb0 + (j << 5);
        float bias = C0[gc];
#pragma unroll
        for (int g = 0; g < 4; g++)
#pragma unroll
          for (int rr = 0; rr < 4; rr++) {
            int gr = rb0 + (i << 5) + (g << 3) + rr;
            F0[(long)gr * H_DIM + gc] = acc[i][j][g * 4 + rr] * (1.0f / 17179869184.0f) + bias;
          }
      }
  }
}

extern "C" void kernel_launch(void* const* d_in, const int* in_sizes, int n_in,
                              void* d_out, int out_size, void* d_ws, size_t ws_size,
                              hipStream_t stream) {
  const float* X     = (const float*)d_in[0];
  const float* W_uv  = (const float*)d_in[1];
  const float* b_uv  = (const float*)d_in[2];
  const float* gamma = (const float*)d_in[3];
  const float* beta  = (const float*)d_in[4];
  const float* W_out = (const float*)d_in[5];
  const float* b_out = (const float*)d_in[6];
  float* out = (float*)d_out;

  char* wp = (char*)d_ws;
  f16* Xh   = (f16*)wp; wp += (long)M_TOT * H_DIM * 2;        // 16 MB
  f16* Wuvt = (f16*)wp; wp += (long)F_DIM * H_DIM * 2;        // 8.65 MB
  f16* Wt   = (f16*)wp; wp += (long)H_DIM * E_DIM * 2;        // 4 MB
  f16* u    = (f16*)wp; wp += (long)M_TOT * E_DIM * 2;        // 32 MB
  f16* vt   = (f16*)wp; wp += (long)M_TOT * E_DIM * 2;        // 32 MB
  f16* qh   = (f16*)wp; wp += (long)M_TOT * SD * 2;           // 2 MB
  f16* kh   = (f16*)wp; wp += (long)M_TOT * SD * 2;           // 2 MB
  f16* sq   = (f16*)wp; wp += (long)B_SZ * S_LEN * S_LEN * 2; // 32 MB
  f16* p    = (f16*)wp; wp += (long)M_TOT * E_DIM * 2;        // 32 MB

  // prep
  cast_f16_k<<<(M_TOT * H_DIM) / (256 * 4), 256, 0, stream>>>(X, Xh, (long)M_TOT * H_DIM);
  transpose_cast_k<<<dim3(F_DIM / 32, H_DIM / 32), 256, 0, stream>>>(W_uv, Wuvt, H_DIM, F_DIM);
  transpose_cast_k<<<dim3(H_DIM / 32, E_DIM / 32), 256, 0, stream>>>(W_out, Wt, E_DIM, H_DIM);

  // u, v_t  (N=4096, slim epilogue)
  mfma_gemm<0><<<dim3(2 * E_DIM / 128, M_TOT / 128, 1), 256, 0, stream>>>(
      Xh, Wuvt, nullptr, u, vt, nullptr, nullptr, b_uv, nullptr, nullptr);

  // q, k  (base 128 cols of W_uv)
  mfma_gemm<4><<<dim3(1, M_TOT / 128, 1), 256, 0, stream>>>(
      Xh, Wuvt + (long)2 * E_DIM * H_DIM, nullptr, nullptr, nullptr, qh, kh,
      b_uv + 2 * E_DIM, gamma, beta);

  // sq = (relu(q@k^T)*2^6)^2
  mfma_gemm<1><<<dim3(S_LEN / 128, S_LEN / 128, B_SZ), 256, 0, stream>>>(
      qh, kh, nullptr, sq, nullptr, nullptr, nullptr, nullptr, nullptr, nullptr);

  // p = u * (sq @ v)
  mfma_gemm<2><<<dim3(E_DIM / 128, S_LEN / 128, B_SZ), 256, 0, stream>>>(
      sq, vt, nullptr, p, u, nullptr, nullptr, nullptr, nullptr, nullptr);

  // out = p @ W_out * 2^-34 + b_out
  mfma_gemm<3><<<dim3(H_DIM / 128, M_TOT / 128, 1), 256, 0, stream>>>(
      p, Wt, out, nullptr, nullptr, nullptr, nullptr, b_out, nullptr, nullptr);
}